// Round 1
// baseline (157.039 us; speedup 1.0000x reference)
//
#include <hip/hip_runtime.h>
#include <hip/hip_bf16.h>
#include <stdint.h>

typedef __attribute__((ext_vector_type(8))) short short8;
typedef __attribute__((ext_vector_type(4))) short short4v;
typedef __attribute__((ext_vector_type(4))) float float4v;

#define MFMA16(a,b,c) __builtin_amdgcn_mfma_f32_16x16x32_bf16((a),(b),(c),0,0,0)

__device__ __forceinline__ short bf16r(float f) {
  union { float f; uint32_t u; } v; v.f = f;
  uint32_t r = v.u + 0x7fffu + ((v.u >> 16) & 1u);
  return (short)(r >> 16);
}

__device__ __forceinline__ void gld_lds16(void* lds, const void* g) {
  __builtin_amdgcn_global_load_lds(
      (const __attribute__((address_space(1))) uint32_t*)g,
      (__attribute__((address_space(3))) uint32_t*)lds, 16, 0, 0);
}

// ---------------- Kernel 1: W transpose+convert -> WT bf16 [3][64][1024] ----
__global__ __launch_bounds__(256) void prep_wt(
    const float* __restrict__ Wk, const float* __restrict__ Wq,
    const float* __restrict__ Wv, short* __restrict__ WT) {
  int idx = blockIdx.x * 256 + threadIdx.x;   // 0 .. 3*64*1024-1
  int w = idx >> 16;
  int rem = idx & 65535;
  int h = rem >> 10;
  int k = rem & 1023;
  const float* W = (w == 0) ? Wk : (w == 1) ? Wq : Wv;
  WT[idx] = bf16r(W[k * 64 + h]);
}

// ---------------- Kernel 2: projection GEMM (bf16 MFMA) --------------------
// x[16384][1024] fp32 @ WT[192][1024] bf16 -> Kg/Qg [16384][64] bf16,
// Vt [4][64][4096] bf16 (transposed for attention B-fragments).
__global__ __launch_bounds__(256) void proj_kernel(
    const float* __restrict__ x, const short* __restrict__ WT,
    short* __restrict__ Kg, short* __restrict__ Qg, short* __restrict__ Vt) {
  __shared__ short xs[64][72];     // +8 pad: A-frag reads 2-way (free)
  __shared__ short wts[192][72];
  const int tid = threadIdx.x;
  const int lane = tid & 63;
  const int w = tid >> 6;
  const int m0 = blockIdx.x * 64;

  float4v acc[12];
#pragma unroll
  for (int i = 0; i < 12; ++i) acc[i] = (float4v){0.f, 0.f, 0.f, 0.f};

  for (int k0 = 0; k0 < 1024; k0 += 64) {
    __syncthreads();
    {  // stage x tile 64x64 fp32 -> bf16
      const int r = tid >> 2;
      const int cb = (tid & 3) * 16;
      const float* src = x + (size_t)(m0 + r) * 1024 + k0 + cb;
#pragma unroll
      for (int j = 0; j < 4; ++j) {
        float4v f = *(const float4v*)(src + j * 4);
        short4v h;
        h.x = bf16r(f.x); h.y = bf16r(f.y); h.z = bf16r(f.z); h.w = bf16r(f.w);
        *(short4v*)(&xs[r][cb + j * 4]) = h;
      }
    }
#pragma unroll
    for (int j = 0; j < 6; ++j) {  // stage WT tile 192x64 bf16
      int chunk = j * 256 + tid;
      int n = chunk >> 3, c = chunk & 7;
      short8 v = *(const short8*)(WT + n * 1024 + k0 + c * 8);
      *(short8*)(&wts[n][c * 8]) = v;
    }
    __syncthreads();

    short8 a0 = *(const short8*)(&xs[w * 16 + (lane & 15)][(lane >> 4) * 8]);
    short8 a1 = *(const short8*)(&xs[w * 16 + (lane & 15)][32 + (lane >> 4) * 8]);
#pragma unroll
    for (int nt = 0; nt < 12; ++nt) {
      const short* bp = &wts[nt * 16 + (lane & 15)][(lane >> 4) * 8];
      short8 b0 = *(const short8*)(bp);
      short8 b1 = *(const short8*)(bp + 32);
      acc[nt] = MFMA16(a0, b0, acc[nt]);
      acc[nt] = MFMA16(a1, b1, acc[nt]);
    }
  }

  const int b = m0 >> 12;
  const int s_base = m0 & 4095;
  const int q_local = w * 16 + ((lane >> 4) << 2);
#pragma unroll
  for (int nt = 0; nt < 12; ++nt) {
    const int wsel = nt >> 2;               // 0:K 1:Q 2:V (d_in order)
    const int h = (nt & 3) * 16 + (lane & 15);
    if (wsel == 2) {                        // V transposed: 4 consecutive s
      short4v pv;
      pv.x = bf16r(acc[nt].x); pv.y = bf16r(acc[nt].y);
      pv.z = bf16r(acc[nt].z); pv.w = bf16r(acc[nt].w);
      *(short4v*)(Vt + (size_t)(b * 64 + h) * 4096 + s_base + q_local) = pv;
    } else {
      short* outp = (wsel == 0) ? Kg : Qg;
#pragma unroll
      for (int i = 0; i < 4; ++i)
        outp[(size_t)(m0 + q_local + i) * 64 + h] = bf16r(acc[nt][i]);
    }
  }
}

// ---------------- Kernel 3: flash attention ---------------------------------
// grid (64, 4); block 256 = 4 waves x 16 q-rows; KV tile = 64.
__global__ __launch_bounds__(256) void attn_kernel(
    const short* __restrict__ Qg, const short* __restrict__ Kg,
    const short* __restrict__ Vt, float* __restrict__ out) {
  __shared__ __align__(16) short Ks[64 * 64];   // swizzled content
  __shared__ __align__(16) short Vs[64 * 64];   // swizzled content (VT rows=h)
  __shared__ __align__(16) short Ps[4][16][72];

  const int tid = threadIdx.x;
  const int lane = tid & 63;
  const int w = tid >> 6;
  const int b = blockIdx.y;
  const int qt = blockIdx.x;
  const int qw = qt * 64 + w * 16;

  short8 aq0, aq1;
  {
    const short* qp = Qg + (size_t)(b * 4096 + qw + (lane & 15)) * 64 + ((lane >> 4) * 8);
    aq0 = *(const short8*)(qp);
    aq1 = *(const short8*)(qp + 32);
  }

  float4v o0 = {0, 0, 0, 0}, o1 = o0, o2 = o0, o3 = o0;
  float mrun[4] = {-1e30f, -1e30f, -1e30f, -1e30f};
  float lsum[4] = {0.f, 0.f, 0.f, 0.f};
  const float scale = 0.125f;

  for (int t = 0; t <= qt; ++t) {
    const int kv0 = t * 64;
    __syncthreads();
#pragma unroll
    for (int j = 0; j < 2; ++j) {   // stage K,V: linear LDS dest, swizzled src
      const int chunk = j * 256 + tid;
      const int row = chunk >> 3;
      const int ss = (chunk & 7) ^ (row & 7);
      gld_lds16(Ks + chunk * 8, Kg + (size_t)(b * 4096 + kv0 + row) * 64 + ss * 8);
      gld_lds16(Vs + chunk * 8, Vt + (size_t)(b * 64 + row) * 4096 + kv0 + ss * 8);
    }
    __syncthreads();

    // S = Q K^T
    float4v s[4];
#pragma unroll
    for (int nt = 0; nt < 4; ++nt) {
      const int rr = nt * 16 + (lane & 15);
      const int sl = (lane >> 4);
      short8 kb0 = *(const short8*)(Ks + rr * 64 + ((sl ^ (rr & 7)) * 8));
      short8 kb1 = *(const short8*)(Ks + rr * 64 + (((sl + 4) ^ (rr & 7)) * 8));
      float4v z = {0, 0, 0, 0};
      z = MFMA16(aq0, kb0, z);
      z = MFMA16(aq1, kb1, z);
      s[nt] = z;
    }

    // scale + causal mask (diagonal tile only)
    if (t == qt) {
#pragma unroll
      for (int nt = 0; nt < 4; ++nt) {
        const int kvg = kv0 + nt * 16 + (lane & 15);
#pragma unroll
        for (int i = 0; i < 4; ++i) {
          const int qg = qw + ((lane >> 4) << 2) + i;
          float v = s[nt][i] * scale;
          s[nt][i] = (kvg <= qg) ? v : -1e30f;
        }
      }
    } else {
#pragma unroll
      for (int nt = 0; nt < 4; ++nt)
#pragma unroll
        for (int i = 0; i < 4; ++i) s[nt][i] *= scale;
    }

    // online softmax (row lives across 16 lanes of a group)
    float pm[4];
#pragma unroll
    for (int i = 0; i < 4; ++i)
      pm[i] = fmaxf(fmaxf(s[0][i], s[1][i]), fmaxf(s[2][i], s[3][i]));
#pragma unroll
    for (int off = 1; off <= 8; off <<= 1)
#pragma unroll
      for (int i = 0; i < 4; ++i) pm[i] = fmaxf(pm[i], __shfl_xor(pm[i], off));

    float alpha[4];
#pragma unroll
    for (int i = 0; i < 4; ++i) {
      const float mn = fmaxf(mrun[i], pm[i]);
      alpha[i] = __expf(mrun[i] - mn);
      mrun[i] = mn;
    }
#pragma unroll
    for (int nt = 0; nt < 4; ++nt)
#pragma unroll
      for (int i = 0; i < 4; ++i) s[nt][i] = __expf(s[nt][i] - mrun[i]);

    float rs[4];
#pragma unroll
    for (int i = 0; i < 4; ++i) rs[i] = (s[0][i] + s[1][i]) + (s[2][i] + s[3][i]);
#pragma unroll
    for (int off = 1; off <= 8; off <<= 1)
#pragma unroll
      for (int i = 0; i < 4; ++i) rs[i] += __shfl_xor(rs[i], off);
#pragma unroll
    for (int i = 0; i < 4; ++i) lsum[i] = lsum[i] * alpha[i] + rs[i];

#pragma unroll
    for (int i = 0; i < 4; ++i) {
      o0[i] *= alpha[i]; o1[i] *= alpha[i]; o2[i] *= alpha[i]; o3[i] *= alpha[i];
    }

    // P -> bf16 -> LDS (A-fragment relayout), own-wave region
#pragma unroll
    for (int nt = 0; nt < 4; ++nt)
#pragma unroll
      for (int i = 0; i < 4; ++i)
        Ps[w][((lane >> 4) << 2) + i][nt * 16 + (lane & 15)] = bf16r(s[nt][i]);

    short8 ap0 = *(const short8*)(&Ps[w][lane & 15][(lane >> 4) * 8]);
    short8 ap1 = *(const short8*)(&Ps[w][lane & 15][32 + (lane >> 4) * 8]);

    // O += P V
#pragma unroll
    for (int ht = 0; ht < 4; ++ht) {
      const int rr = ht * 16 + (lane & 15);
      const int sl = (lane >> 4);
      short8 vb0 = *(const short8*)(Vs + rr * 64 + ((sl ^ (rr & 7)) * 8));
      short8 vb1 = *(const short8*)(Vs + rr * 64 + (((sl + 4) ^ (rr & 7)) * 8));
      float4v* op = (ht == 0) ? &o0 : (ht == 1) ? &o1 : (ht == 2) ? &o2 : &o3;
      *op = MFMA16(ap0, vb0, *op);
      *op = MFMA16(ap1, vb1, *op);
    }
  }

  float inv[4];
#pragma unroll
  for (int i = 0; i < 4; ++i) inv[i] = 1.0f / lsum[i];
#pragma unroll
  for (int ht = 0; ht < 4; ++ht) {
    const float4v ov = (ht == 0) ? o0 : (ht == 1) ? o1 : (ht == 2) ? o2 : o3;
#pragma unroll
    for (int i = 0; i < 4; ++i) {
      const int q = qw + ((lane >> 4) << 2) + i;
      out[(size_t)(b * 4096 + q) * 64 + ht * 16 + (lane & 15)] = ov[i] * inv[i];
    }
  }
}

extern "C" void kernel_launch(void* const* d_in, const int* in_sizes, int n_in,
                              void* d_out, int out_size, void* d_ws, size_t ws_size,
                              hipStream_t stream) {
  const float* x  = (const float*)d_in[0];
  const float* Wk = (const float*)d_in[1];
  const float* Wq = (const float*)d_in[2];
  const float* Wv = (const float*)d_in[3];

  char* ws = (char*)d_ws;
  short* WT = (short*)ws;                                  // 393216 B
  short* Kg = (short*)(ws + 393216);                       // 2 MB
  short* Qg = (short*)(ws + 393216 + 2097152);             // 2 MB
  short* Vt = (short*)(ws + 393216 + 2 * 2097152);         // 2 MB

  prep_wt<<<dim3(768), dim3(256), 0, stream>>>(Wk, Wq, Wv, WT);
  proj_kernel<<<dim3(256), dim3(256), 0, stream>>>(x, WT, Kg, Qg, Vt);
  attn_kernel<<<dim3(64, 4), dim3(256), 0, stream>>>(Qg, Kg, Vt, (float*)d_out);
}